// Round 1
// baseline (919.656 us; speedup 1.0000x reference)
//
#include <hip/hip_runtime.h>
#include <hip/hip_bf16.h>

#define N_NODES 1024
#define R_SRC   8192
#define E_DIM   1024
#define H_HEADS 4
#define DH_DIM  256
#define D_MAXN  48

// ---------------------------------------------------------------------------
// Generic fp32 NT GEMM: C[M,N] = act(A[M,K] @ W[N,K]^T + bias[N])
// Both A and W are K-major (row-major with K contiguous) -> coalesced loads.
// 64x64 tile, BK=16, 256 threads, 4x4 micro-tile per thread.
// rowmask: if non-null and rowmask[m]==0, row m of C is written as 0
// (including bias), matching the reference's degree-0 masking.
// ---------------------------------------------------------------------------
#define BM 64
#define BN 64
#define BK 16

__global__ __launch_bounds__(256) void gemm_nt(
    const float* __restrict__ A, const float* __restrict__ W,
    const float* __restrict__ bias, float* __restrict__ C,
    int M, int N, int K, int do_relu, const int* __restrict__ rowmask)
{
    __shared__ float As[BK][BM + 4];
    __shared__ float Ws[BK][BN + 4];

    const int t  = threadIdx.x;
    const int tx = t & 15;        // 0..15 -> N
    const int ty = t >> 4;        // 0..15 -> M
    const int m0 = blockIdx.y * BM;
    const int n0 = blockIdx.x * BN;

    float acc[4][4] = {};

    const int lr = t >> 2;          // 0..63: row within tile
    const int lc = (t & 3) << 2;    // 0,4,8,12: k-offset within tile
    const float* Ap = A + (size_t)(m0 + lr) * K + lc;
    const float* Wp = W + (size_t)(n0 + lr) * K + lc;

    for (int k0 = 0; k0 < K; k0 += BK) {
        float4 av = *(const float4*)(Ap + k0);
        float4 wv = *(const float4*)(Wp + k0);
        As[lc + 0][lr] = av.x; As[lc + 1][lr] = av.y;
        As[lc + 2][lr] = av.z; As[lc + 3][lr] = av.w;
        Ws[lc + 0][lr] = wv.x; Ws[lc + 1][lr] = wv.y;
        Ws[lc + 2][lr] = wv.z; Ws[lc + 3][lr] = wv.w;
        __syncthreads();
#pragma unroll
        for (int kk = 0; kk < BK; ++kk) {
            float a[4], b[4];
#pragma unroll
            for (int i = 0; i < 4; ++i) a[i] = As[kk][ty * 4 + i];
#pragma unroll
            for (int j = 0; j < 4; ++j) b[j] = Ws[kk][tx * 4 + j];
#pragma unroll
            for (int i = 0; i < 4; ++i)
#pragma unroll
                for (int j = 0; j < 4; ++j)
                    acc[i][j] = fmaf(a[i], b[j], acc[i][j]);
        }
        __syncthreads();
    }

#pragma unroll
    for (int i = 0; i < 4; ++i) {
        const int m = m0 + ty * 4 + i;
        const bool zero = (rowmask != nullptr) && (rowmask[m] == 0);
#pragma unroll
        for (int j = 0; j < 4; ++j) {
            const int n = n0 + tx * 4 + j;
            float v = acc[i][j] + bias[n];
            if (do_relu) v = fmaxf(v, 0.0f);
            if (zero) v = 0.0f;
            C[(size_t)m * N + n] = v;
        }
    }
}

// ---------------------------------------------------------------------------
// Per-node neighbor list: first D_MAXN set columns of adj[n, :] in ascending
// column order (matches the reference's stable argsort(-adj)), plus total
// degree. One wave (64 lanes) per node; ballot+popcount keeps order.
// ---------------------------------------------------------------------------
__global__ __launch_bounds__(64) void build_neigh(
    const float* __restrict__ adj, int* __restrict__ neigh, int* __restrict__ deg)
{
    const int n    = blockIdx.x;
    const int lane = threadIdx.x;
    const float* row = adj + (size_t)n * R_SRC;
    int total = 0;
    for (int base = 0; base < R_SRC; base += 64) {
        const float v = row[base + lane];
        const unsigned long long mask = __ballot(v != 0.0f);
        const int pos = total + __popcll(mask & ((1ULL << lane) - 1ULL));
        if (v != 0.0f && pos < D_MAXN) neigh[n * D_MAXN + pos] = base + lane;
        total += __popcll(mask);
    }
    if (lane == 0) deg[n] = total;
}

// ---------------------------------------------------------------------------
// Per-node multi-head attention over gathered neighbors.
// Block = 256 threads = 4 waves; wave h owns head h (DH=256 -> 4 floats/lane).
// ---------------------------------------------------------------------------
__global__ __launch_bounds__(256) void attn_kernel(
    const float* __restrict__ Q, const float* __restrict__ Ksrc,
    const float* __restrict__ Vsrc, const int* __restrict__ neigh,
    const int* __restrict__ deg, float* __restrict__ attn_out)
{
    const int n    = blockIdx.x;
    const int t    = threadIdx.x;
    const int h    = t >> 6;     // wave index == head
    const int lane = t & 63;

    const int degree = deg[n];
    float* orow = attn_out + (size_t)n * E_DIM;

    if (degree == 0) {
        // output for this node is zeroed in the final GEMM epilogue anyway;
        // write zeros so downstream reads are deterministic.
        for (int j = t; j < E_DIM; j += 256) orow[j] = 0.0f;
        return;
    }
    const int dv = degree < D_MAXN ? degree : D_MAXN;

    __shared__ float s_scores[H_HEADS][D_MAXN];
    __shared__ float s_w[H_HEADS][D_MAXN];
    __shared__ int   s_neigh[D_MAXN];

    if (t < dv) s_neigh[t] = neigh[n * D_MAXN + t];
    __syncthreads();

    // q fragment for this head: lane holds elements lane + j*64
    const float* qrow = Q + (size_t)n * E_DIM + h * DH_DIM;
    float q0 = qrow[lane], q1 = qrow[lane + 64], q2 = qrow[lane + 128], q3 = qrow[lane + 192];
    const float scale = 0.0625f;  // 1/sqrt(256)

    for (int d = 0; d < dv; ++d) {
        const int r = s_neigh[d];
        const float* kp = Ksrc + (size_t)r * E_DIM + h * DH_DIM;
        float s = q0 * kp[lane] + q1 * kp[lane + 64] + q2 * kp[lane + 128] + q3 * kp[lane + 192];
#pragma unroll
        for (int off = 32; off > 0; off >>= 1) s += __shfl_xor(s, off);
        if (lane == 0) s_scores[h][d] = s * scale;
    }
    __syncthreads();

    // softmax over the dv valid slots (per head, within the wave)
    {
        float v = (lane < dv) ? s_scores[h][lane] : -3.4e38f;
        float mx = v;
#pragma unroll
        for (int off = 32; off > 0; off >>= 1) mx = fmaxf(mx, __shfl_xor(mx, off));
        float e = (lane < dv) ? __expf(v - mx) : 0.0f;
        float sum = e;
#pragma unroll
        for (int off = 32; off > 0; off >>= 1) sum += __shfl_xor(sum, off);
        if (lane < dv) s_w[h][lane] = e / sum;
    }
    __syncthreads();

    // out[h,:] = sum_d w_d * V[neigh[d]][h,:]
    float acc0 = 0.f, acc1 = 0.f, acc2 = 0.f, acc3 = 0.f;
    for (int d = 0; d < dv; ++d) {
        const int r = s_neigh[d];
        const float w = s_w[h][d];
        const float* vp = Vsrc + (size_t)r * E_DIM + h * DH_DIM;
        acc0 = fmaf(w, vp[lane],       acc0);
        acc1 = fmaf(w, vp[lane + 64],  acc1);
        acc2 = fmaf(w, vp[lane + 128], acc2);
        acc3 = fmaf(w, vp[lane + 192], acc3);
    }
    orow[h * DH_DIM + lane]       = acc0;
    orow[h * DH_DIM + lane + 64]  = acc1;
    orow[h * DH_DIM + lane + 128] = acc2;
    orow[h * DH_DIM + lane + 192] = acc3;
}

// ---------------------------------------------------------------------------
extern "C" void kernel_launch(void* const* d_in, const int* in_sizes, int n_in,
                              void* d_out, int out_size, void* d_ws, size_t ws_size,
                              hipStream_t stream)
{
    const float* target  = (const float*)d_in[0];   // [N, E]
    const float* source  = (const float*)d_in[1];   // [R, E]
    const float* adj     = (const float*)d_in[2];   // [N, R]
    const float* W_trans = (const float*)d_in[3];   // [E, E]
    const float* b_trans = (const float*)d_in[4];   // [E]
    const float* in_w    = (const float*)d_in[5];   // [3E, E]
    const float* in_b    = (const float*)d_in[6];   // [3E]
    const float* out_w   = (const float*)d_in[7];   // [E, E]
    const float* out_b   = (const float*)d_in[8];   // [E]
    float* out = (float*)d_out;                     // [N, E]

    char* ws = (char*)d_ws;
    float* src_relu = (float*)ws;  ws += (size_t)R_SRC * E_DIM * sizeof(float);
    float* Ksrc     = (float*)ws;  ws += (size_t)R_SRC * E_DIM * sizeof(float);
    float* Vsrc     = (float*)ws;  ws += (size_t)R_SRC * E_DIM * sizeof(float);
    float* Qm       = (float*)ws;  ws += (size_t)N_NODES * E_DIM * sizeof(float);
    float* attn_out = (float*)ws;  ws += (size_t)N_NODES * E_DIM * sizeof(float);
    int*   neigh    = (int*)ws;    ws += (size_t)N_NODES * D_MAXN * sizeof(int);
    int*   deg      = (int*)ws;    ws += (size_t)N_NODES * sizeof(int);

    // 1) neighbor lists (independent of GEMMs)
    build_neigh<<<N_NODES, 64, 0, stream>>>(adj, neigh, deg);

    // 2) src_relu = relu(source @ W_trans^T + b_trans)   [R, E]
    gemm_nt<<<dim3(E_DIM / BN, R_SRC / BM), 256, 0, stream>>>(
        source, W_trans, b_trans, src_relu, R_SRC, E_DIM, E_DIM, 1, nullptr);

    // 3) K = src_relu @ Wk^T + bk ; V = src_relu @ Wv^T + bv   [R, E]
    gemm_nt<<<dim3(E_DIM / BN, R_SRC / BM), 256, 0, stream>>>(
        src_relu, in_w + (size_t)E_DIM * E_DIM, in_b + E_DIM,
        Ksrc, R_SRC, E_DIM, E_DIM, 0, nullptr);
    gemm_nt<<<dim3(E_DIM / BN, R_SRC / BM), 256, 0, stream>>>(
        src_relu, in_w + (size_t)2 * E_DIM * E_DIM, in_b + 2 * E_DIM,
        Vsrc, R_SRC, E_DIM, E_DIM, 0, nullptr);

    // 4) Q = target @ Wq^T + bq   [N, E]
    gemm_nt<<<dim3(E_DIM / BN, N_NODES / BM), 256, 0, stream>>>(
        target, in_w, in_b, Qm, N_NODES, E_DIM, E_DIM, 0, nullptr);

    // 5) attention
    attn_kernel<<<N_NODES, 256, 0, stream>>>(Qm, Ksrc, Vsrc, neigh, deg, attn_out);

    // 6) out = attn_out @ out_w^T + out_b, rows with deg==0 forced to 0
    gemm_nt<<<dim3(E_DIM / BN, N_NODES / BM), 256, 0, stream>>>(
        attn_out, out_w, out_b, out, N_NODES, E_DIM, E_DIM, 0, deg);
}

// Round 3
// 224.695 us; speedup vs baseline: 4.0929x; 4.0929x over previous
//
#include <hip/hip_runtime.h>

#define N_NODES 1024
#define R_SRC   8192
#define E_DIM   1024
#define H_HEADS 4
#define DH_DIM  256
#define D_MAXN  48

typedef __attribute__((ext_vector_type(8))) short short8;
typedef __attribute__((ext_vector_type(4))) float f32x4;

__device__ __forceinline__ unsigned short f2bf(float f) {
    unsigned u = __float_as_uint(f);
    unsigned r = u + 0x7fffu + ((u >> 16) & 1u);   // round-to-nearest-even
    return (unsigned short)(r >> 16);
}
__device__ __forceinline__ float bf2f(unsigned short b) {
    return __uint_as_float(((unsigned)b) << 16);
}
__device__ __forceinline__ void gload16(const void* g, void* l) {
    __builtin_amdgcn_global_load_lds(
        (const __attribute__((address_space(1))) unsigned int*)g,
        (__attribute__((address_space(3))) unsigned int*)l,
        16, 0, 0);
}

// ---------------------------------------------------------------------------
// fp32 -> bf16 conversion, vectorized (float4 in, ushort4 out)
// ---------------------------------------------------------------------------
__global__ __launch_bounds__(256) void f2bf_kernel(
    const float* __restrict__ in, unsigned short* __restrict__ out, int n4)
{
    int i = blockIdx.x * 256 + threadIdx.x;
    if (i < n4) {
        float4 v = ((const float4*)in)[i];
        ushort4 o;
        o.x = f2bf(v.x); o.y = f2bf(v.y); o.z = f2bf(v.z); o.w = f2bf(v.w);
        ((ushort4*)out)[i] = o;
    }
}

// ---------------------------------------------------------------------------
// bf16 MFMA NT GEMM (m97 structure): C[M,N] = act(A[M,K] @ W[N,K]^T + bias)
// 128x128 tile, BK=32, 256 threads = 4 waves (2x2), 4x4 16x16x32 frags/wave.
// A, W are bf16 (ushort bits), K-contiguous. C is f32 or bf16 (OUTBF).
// MASK: rows with rowmask[r]==0 forced to 0 (incl. bias).
// ---------------------------------------------------------------------------
template<int RELU, int OUTBF, int MASK>
__global__ __launch_bounds__(256) void gemm_mfma(
    const unsigned short* __restrict__ A, const unsigned short* __restrict__ W,
    const float* __restrict__ bias, void* __restrict__ Cout,
    int M, int N, int K, const int* __restrict__ rowmask)
{
    __shared__ __align__(16) unsigned short As[128 * 32];
    __shared__ __align__(16) unsigned short Ws[128 * 32];

    const int t  = threadIdx.x;
    const int m0 = blockIdx.y * 128;
    const int n0 = blockIdx.x * 128;

    const int w  = t >> 6, l = t & 63;
    const int wr = (w >> 1) * 64;       // wave row offset in tile
    const int wc = (w & 1) * 64;        // wave col offset in tile
    const int lr = l & 15;              // row/col within 16x16 frag
    const int kg = (l >> 4) * 8;        // k-group offset (8 contiguous bf16)

    f32x4 acc[4][4] = {};

    // staging: 16KB total per K-step -> each thread stages 2x16B of A, 2x16B of W.
    // LDS is linear [128][32] bf16; 16B chunk tc holds row tc/4, k-cols (tc%4)*8..+7.
    const int tc0 = t, tc1 = t + 256;
    const unsigned short* gA0 = A + (size_t)(m0 + (tc0 >> 2)) * K + (tc0 & 3) * 8;
    const unsigned short* gA1 = A + (size_t)(m0 + (tc1 >> 2)) * K + (tc1 & 3) * 8;
    const unsigned short* gW0 = W + (size_t)(n0 + (tc0 >> 2)) * K + (tc0 & 3) * 8;
    const unsigned short* gW1 = W + (size_t)(n0 + (tc1 >> 2)) * K + (tc1 & 3) * 8;
    unsigned short* lA0 = &As[tc0 * 8];
    unsigned short* lA1 = &As[tc1 * 8];
    unsigned short* lW0 = &Ws[tc0 * 8];
    unsigned short* lW1 = &Ws[tc1 * 8];

    for (int k0 = 0; k0 < K; k0 += 32) {
        gload16(gA0 + k0, lA0);
        gload16(gA1 + k0, lA1);
        gload16(gW0 + k0, lW0);
        gload16(gW1 + k0, lW1);
        __syncthreads();   // drains vmcnt(0): staged tile visible

        short8 af[4], bw[4];
#pragma unroll
        for (int i = 0; i < 4; ++i)
            af[i] = *(const short8*)&As[(wr + i * 16 + lr) * 32 + kg];
#pragma unroll
        for (int j = 0; j < 4; ++j)
            bw[j] = *(const short8*)&Ws[(wc + j * 16 + lr) * 32 + kg];
#pragma unroll
        for (int i = 0; i < 4; ++i)
#pragma unroll
            for (int j = 0; j < 4; ++j)
                acc[i][j] = __builtin_amdgcn_mfma_f32_16x16x32_bf16(
                    af[i], bw[j], acc[i][j], 0, 0, 0);
        __syncthreads();   // all waves done reading before next stage overwrites
    }

    // epilogue: C/D layout col = lane&15, row = (lane>>4)*4 + q
#pragma unroll
    for (int j = 0; j < 4; ++j) {
        const int c  = n0 + wc + j * 16 + (l & 15);
        const float bv = bias[c];
#pragma unroll
        for (int i = 0; i < 4; ++i) {
            const int rbase = m0 + wr + i * 16 + (l >> 4) * 4;
#pragma unroll
            for (int q = 0; q < 4; ++q) {
                const int r = rbase + q;
                float x = acc[i][j][q] + bv;
                if (RELU) x = fmaxf(x, 0.0f);
                if (MASK) { if (rowmask[r] == 0) x = 0.0f; }
                if (OUTBF) ((unsigned short*)Cout)[(size_t)r * N + c] = f2bf(x);
                else       ((float*)Cout)[(size_t)r * N + c] = x;
            }
        }
    }
}

// ---------------------------------------------------------------------------
// Per-node neighbor list (ascending column order == reference's stable argsort)
// ---------------------------------------------------------------------------
__global__ __launch_bounds__(64) void build_neigh(
    const float* __restrict__ adj, int* __restrict__ neigh, int* __restrict__ deg)
{
    const int n    = blockIdx.x;
    const int lane = threadIdx.x;
    const float* row = adj + (size_t)n * R_SRC;
    int total = 0;
    for (int base = 0; base < R_SRC; base += 64) {
        const float v = row[base + lane];
        const unsigned long long mask = __ballot(v != 0.0f);
        const int pos = total + __popcll(mask & ((1ULL << lane) - 1ULL));
        if (v != 0.0f && pos < D_MAXN) neigh[n * D_MAXN + pos] = base + lane;
        total += __popcll(mask);
    }
    if (lane == 0) deg[n] = total;
}

// ---------------------------------------------------------------------------
// Per-node multi-head attention over gathered neighbors (K/V in bf16).
// Block = 256 = 4 waves; wave h owns head h (DH=256 -> 4 floats/lane).
// Output written as bf16 (input to the final GEMM).
// ---------------------------------------------------------------------------
__global__ __launch_bounds__(256) void attn_kernel(
    const float* __restrict__ Q, const unsigned short* __restrict__ Ksrc,
    const unsigned short* __restrict__ Vsrc, const int* __restrict__ neigh,
    const int* __restrict__ deg, unsigned short* __restrict__ attn_out)
{
    const int n    = blockIdx.x;
    const int t    = threadIdx.x;
    const int h    = t >> 6;
    const int lane = t & 63;

    const int degree = deg[n];
    unsigned short* orow = attn_out + (size_t)n * E_DIM;

    if (degree == 0) {
        for (int j = t; j < E_DIM; j += 256) orow[j] = 0;   // bf16 zero
        return;
    }
    const int dv = degree < D_MAXN ? degree : D_MAXN;

    __shared__ float s_scores[H_HEADS][D_MAXN];
    __shared__ float s_w[H_HEADS][D_MAXN];
    __shared__ int   s_neigh[D_MAXN];

    if (t < dv) s_neigh[t] = neigh[n * D_MAXN + t];
    __syncthreads();

    const float* qrow = Q + (size_t)n * E_DIM + h * DH_DIM;
    float q0 = qrow[lane], q1 = qrow[lane + 64], q2 = qrow[lane + 128], q3 = qrow[lane + 192];
    const float scale = 0.0625f;  // 1/sqrt(256)

    for (int d = 0; d < dv; ++d) {
        const int r = s_neigh[d];
        const unsigned short* kp = Ksrc + (size_t)r * E_DIM + h * DH_DIM;
        float s = q0 * bf2f(kp[lane]) + q1 * bf2f(kp[lane + 64])
                + q2 * bf2f(kp[lane + 128]) + q3 * bf2f(kp[lane + 192]);
#pragma unroll
        for (int off = 32; off > 0; off >>= 1) s += __shfl_xor(s, off);
        if (lane == 0) s_scores[h][d] = s * scale;
    }
    __syncthreads();

    {
        float v = (lane < dv) ? s_scores[h][lane] : -3.4e38f;
        float mx = v;
#pragma unroll
        for (int off = 32; off > 0; off >>= 1) mx = fmaxf(mx, __shfl_xor(mx, off));
        float e = (lane < dv) ? __expf(v - mx) : 0.0f;
        float sum = e;
#pragma unroll
        for (int off = 32; off > 0; off >>= 1) sum += __shfl_xor(sum, off);
        if (lane < dv) s_w[h][lane] = e / sum;
    }
    __syncthreads();

    float acc0 = 0.f, acc1 = 0.f, acc2 = 0.f, acc3 = 0.f;
    for (int d = 0; d < dv; ++d) {
        const int r = s_neigh[d];
        const float wgt = s_w[h][d];
        const unsigned short* vp = Vsrc + (size_t)r * E_DIM + h * DH_DIM;
        acc0 = fmaf(wgt, bf2f(vp[lane]),       acc0);
        acc1 = fmaf(wgt, bf2f(vp[lane + 64]),  acc1);
        acc2 = fmaf(wgt, bf2f(vp[lane + 128]), acc2);
        acc3 = fmaf(wgt, bf2f(vp[lane + 192]), acc3);
    }
    orow[h * DH_DIM + lane]       = f2bf(acc0);
    orow[h * DH_DIM + lane + 64]  = f2bf(acc1);
    orow[h * DH_DIM + lane + 128] = f2bf(acc2);
    orow[h * DH_DIM + lane + 192] = f2bf(acc3);
}

// ---------------------------------------------------------------------------
extern "C" void kernel_launch(void* const* d_in, const int* in_sizes, int n_in,
                              void* d_out, int out_size, void* d_ws, size_t ws_size,
                              hipStream_t stream)
{
    const float* target  = (const float*)d_in[0];   // [N, E]
    const float* source  = (const float*)d_in[1];   // [R, E]
    const float* adj     = (const float*)d_in[2];   // [N, R]
    const float* W_trans = (const float*)d_in[3];   // [E, E]
    const float* b_trans = (const float*)d_in[4];   // [E]
    const float* in_w    = (const float*)d_in[5];   // [3E, E]
    const float* in_b    = (const float*)d_in[6];   // [3E]
    const float* out_w   = (const float*)d_in[7];   // [E, E]
    const float* out_b   = (const float*)d_in[8];   // [E]
    float* out = (float*)d_out;                     // [N, E] f32

    char* ws = (char*)d_ws;
    unsigned short* src_bf    = (unsigned short*)ws; ws += (size_t)R_SRC * E_DIM * 2;
    unsigned short* wt_bf     = (unsigned short*)ws; ws += (size_t)E_DIM * E_DIM * 2;
    unsigned short* inw_bf    = (unsigned short*)ws; ws += (size_t)3 * E_DIM * E_DIM * 2;
    unsigned short* outw_bf   = (unsigned short*)ws; ws += (size_t)E_DIM * E_DIM * 2;
    unsigned short* tgt_bf    = (unsigned short*)ws; ws += (size_t)N_NODES * E_DIM * 2;
    unsigned short* srcrel_bf = (unsigned short*)ws; ws += (size_t)R_SRC * E_DIM * 2;
    unsigned short* K_bf      = (unsigned short*)ws; ws += (size_t)R_SRC * E_DIM * 2;
    unsigned short* V_bf      = (unsigned short*)ws; ws += (size_t)R_SRC * E_DIM * 2;
    float*          Qm        = (float*)ws;          ws += (size_t)N_NODES * E_DIM * 4;
    unsigned short* attn_bf   = (unsigned short*)ws; ws += (size_t)N_NODES * E_DIM * 2;
    int*            neigh     = (int*)ws;            ws += (size_t)N_NODES * D_MAXN * 4;
    int*            deg       = (int*)ws;            ws += (size_t)N_NODES * 4;

    // neighbor lists (independent)
    build_neigh<<<N_NODES, 64, 0, stream>>>(adj, neigh, deg);

    // fp32 -> bf16 conversions of all GEMM operands
    auto conv = [&](const float* src, unsigned short* dst, size_t n) {
        int n4 = (int)(n / 4);
        f2bf_kernel<<<(n4 + 255) / 256, 256, 0, stream>>>(src, dst, n4);
    };
    conv(source,  src_bf,  (size_t)R_SRC * E_DIM);
    conv(W_trans, wt_bf,   (size_t)E_DIM * E_DIM);
    conv(in_w,    inw_bf,  (size_t)3 * E_DIM * E_DIM);
    conv(out_w,   outw_bf, (size_t)E_DIM * E_DIM);
    conv(target,  tgt_bf,  (size_t)N_NODES * E_DIM);

    const size_t EE = (size_t)E_DIM * E_DIM;

    // src_relu = relu(source @ W_trans^T + b_trans)        [R, E] bf16
    gemm_mfma<1, 1, 0><<<dim3(E_DIM / 128, R_SRC / 128), 256, 0, stream>>>(
        src_bf, wt_bf, b_trans, srcrel_bf, R_SRC, E_DIM, E_DIM, nullptr);

    // K = src_relu @ Wk^T + bk ; V = src_relu @ Wv^T + bv  [R, E] bf16
    gemm_mfma<0, 1, 0><<<dim3(E_DIM / 128, R_SRC / 128), 256, 0, stream>>>(
        srcrel_bf, inw_bf + EE, in_b + E_DIM, K_bf, R_SRC, E_DIM, E_DIM, nullptr);
    gemm_mfma<0, 1, 0><<<dim3(E_DIM / 128, R_SRC / 128), 256, 0, stream>>>(
        srcrel_bf, inw_bf + 2 * EE, in_b + 2 * E_DIM, V_bf, R_SRC, E_DIM, E_DIM, nullptr);

    // Q = target @ Wq^T + bq                               [N, E] f32
    gemm_mfma<0, 0, 0><<<dim3(E_DIM / 128, N_NODES / 128), 256, 0, stream>>>(
        tgt_bf, inw_bf, in_b, Qm, N_NODES, E_DIM, E_DIM, nullptr);

    // attention -> bf16
    attn_kernel<<<N_NODES, 256, 0, stream>>>(Qm, K_bf, V_bf, neigh, deg, attn_bf);

    // out = attn_out @ out_w^T + out_b, deg==0 rows zeroed  [N, E] f32
    gemm_mfma<0, 0, 1><<<dim3(E_DIM / 128, N_NODES / 128), 256, 0, stream>>>(
        attn_bf, outw_bf, out_b, out, N_NODES, E_DIM, E_DIM, deg);
}

// Round 4
// 183.462 us; speedup vs baseline: 5.0128x; 1.2248x over previous
//
#include <hip/hip_runtime.h>

#define N_NODES 1024
#define R_SRC   8192
#define E_DIM   1024
#define H_HEADS 4
#define DH_DIM  256
#define D_MAXN  48

typedef __attribute__((ext_vector_type(8))) short short8;
typedef __attribute__((ext_vector_type(4))) float f32x4;

__device__ __forceinline__ unsigned short f2bf(float f) {
    unsigned u = __float_as_uint(f);
    unsigned r = u + 0x7fffu + ((u >> 16) & 1u);   // round-to-nearest-even
    return (unsigned short)(r >> 16);
}
__device__ __forceinline__ float bf2f(unsigned short b) {
    return __uint_as_float(((unsigned)b) << 16);
}
__device__ __forceinline__ void gload16(const void* g, void* l) {
    __builtin_amdgcn_global_load_lds(
        (const __attribute__((address_space(1))) unsigned int*)g,
        (__attribute__((address_space(3))) unsigned int*)l,
        16, 0, 0);
}

// ---------------------------------------------------------------------------
// Batched fp32 -> bf16 conversion: all 5 operands in ONE dispatch.
// ---------------------------------------------------------------------------
struct ConvArgs {
    const float* s[5];
    unsigned short* d[5];
    unsigned off[6];   // prefix offsets in float4 units; off[5] = total
};

__global__ __launch_bounds__(256) void f2bf_multi(ConvArgs a)
{
    unsigned i = blockIdx.x * 256 + threadIdx.x;
    if (i >= a.off[5]) return;
    int seg = 0;
#pragma unroll
    for (int s = 1; s < 5; ++s) seg += (i >= a.off[s]);
    unsigned j = i - a.off[seg];
    float4 v = ((const float4*)a.s[seg])[j];
    ushort4 o;
    o.x = f2bf(v.x); o.y = f2bf(v.y); o.z = f2bf(v.z); o.w = f2bf(v.w);
    ((ushort4*)a.d[seg])[j] = o;
}

// ---------------------------------------------------------------------------
// bf16 MFMA NT GEMM (m97 structure): C[M,N] = act(A[M,K] @ W[N,K]^T + bias)
// 128x128 tile, BK=32, 256 threads = 4 waves (2x2), 4x4 16x16x32 frags/wave.
// ---------------------------------------------------------------------------
template<int RELU, int OUTBF, int MASK>
__global__ __launch_bounds__(256) void gemm_mfma(
    const unsigned short* __restrict__ A, const unsigned short* __restrict__ W,
    const float* __restrict__ bias, void* __restrict__ Cout,
    int M, int N, int K, const int* __restrict__ rowmask)
{
    __shared__ __align__(16) unsigned short As[128 * 32];
    __shared__ __align__(16) unsigned short Ws[128 * 32];

    const int t  = threadIdx.x;
    const int m0 = blockIdx.y * 128;
    const int n0 = blockIdx.x * 128;

    const int w  = t >> 6, l = t & 63;
    const int wr = (w >> 1) * 64;
    const int wc = (w & 1) * 64;
    const int lr = l & 15;
    const int kg = (l >> 4) * 8;

    f32x4 acc[4][4] = {};

    const int tc0 = t, tc1 = t + 256;
    const unsigned short* gA0 = A + (size_t)(m0 + (tc0 >> 2)) * K + (tc0 & 3) * 8;
    const unsigned short* gA1 = A + (size_t)(m0 + (tc1 >> 2)) * K + (tc1 & 3) * 8;
    const unsigned short* gW0 = W + (size_t)(n0 + (tc0 >> 2)) * K + (tc0 & 3) * 8;
    const unsigned short* gW1 = W + (size_t)(n0 + (tc1 >> 2)) * K + (tc1 & 3) * 8;
    unsigned short* lA0 = &As[tc0 * 8];
    unsigned short* lA1 = &As[tc1 * 8];
    unsigned short* lW0 = &Ws[tc0 * 8];
    unsigned short* lW1 = &Ws[tc1 * 8];

    for (int k0 = 0; k0 < K; k0 += 32) {
        gload16(gA0 + k0, lA0);
        gload16(gA1 + k0, lA1);
        gload16(gW0 + k0, lW0);
        gload16(gW1 + k0, lW1);
        __syncthreads();

        short8 af[4], bw[4];
#pragma unroll
        for (int i = 0; i < 4; ++i)
            af[i] = *(const short8*)&As[(wr + i * 16 + lr) * 32 + kg];
#pragma unroll
        for (int j = 0; j < 4; ++j)
            bw[j] = *(const short8*)&Ws[(wc + j * 16 + lr) * 32 + kg];
#pragma unroll
        for (int i = 0; i < 4; ++i)
#pragma unroll
            for (int j = 0; j < 4; ++j)
                acc[i][j] = __builtin_amdgcn_mfma_f32_16x16x32_bf16(
                    af[i], bw[j], acc[i][j], 0, 0, 0);
        __syncthreads();
    }

#pragma unroll
    for (int j = 0; j < 4; ++j) {
        const int c  = n0 + wc + j * 16 + (l & 15);
        const float bv = bias[c];
#pragma unroll
        for (int i = 0; i < 4; ++i) {
            const int rbase = m0 + wr + i * 16 + (l >> 4) * 4;
#pragma unroll
            for (int q = 0; q < 4; ++q) {
                const int r = rbase + q;
                float x = acc[i][j][q] + bv;
                if (RELU) x = fmaxf(x, 0.0f);
                if (MASK) { if (rowmask[r] == 0) x = 0.0f; }
                if (OUTBF) ((unsigned short*)Cout)[(size_t)r * N + c] = f2bf(x);
                else       ((float*)Cout)[(size_t)r * N + c] = x;
            }
        }
    }
}

// ---------------------------------------------------------------------------
// Parallel neighbor-list build: 256 threads = 4 waves per node; wave w owns
// columns [w*2048, (w+1)*2048). Single pass: each wave records its first
// <=48 set columns (ascending) in LDS + its total count; a 4-way prefix then
// places entries at their global rank. Global rank < 48 implies local
// rank < 48, so nothing needed is lost.
// ---------------------------------------------------------------------------
__global__ __launch_bounds__(256) void build_neigh(
    const float* __restrict__ adj, int* __restrict__ neigh, int* __restrict__ deg)
{
    const int n    = blockIdx.x;
    const int t    = threadIdx.x;
    const int w    = t >> 6;
    const int lane = t & 63;
    const float* row = adj + (size_t)n * R_SRC;

    __shared__ int s_cnt[4];
    __shared__ int s_idx[4][D_MAXN];

    const int seg0 = w * (R_SRC / 4);
    const unsigned long long lower = (1ULL << lane) - 1ULL;
    int total = 0;

    for (int base = seg0; base < seg0 + R_SRC / 4; base += 256) {
        const float v0 = row[base + lane];
        const float v1 = row[base + 64 + lane];
        const float v2 = row[base + 128 + lane];
        const float v3 = row[base + 192 + lane];
        const unsigned long long m0 = __ballot(v0 != 0.0f);
        const unsigned long long m1 = __ballot(v1 != 0.0f);
        const unsigned long long m2 = __ballot(v2 != 0.0f);
        const unsigned long long m3 = __ballot(v3 != 0.0f);
        int p;
        p = total + __popcll(m0 & lower);
        if (v0 != 0.0f && p < D_MAXN) s_idx[w][p] = base + lane;
        total += __popcll(m0);
        p = total + __popcll(m1 & lower);
        if (v1 != 0.0f && p < D_MAXN) s_idx[w][p] = base + 64 + lane;
        total += __popcll(m1);
        p = total + __popcll(m2 & lower);
        if (v2 != 0.0f && p < D_MAXN) s_idx[w][p] = base + 128 + lane;
        total += __popcll(m2);
        p = total + __popcll(m3 & lower);
        if (v3 != 0.0f && p < D_MAXN) s_idx[w][p] = base + 192 + lane;
        total += __popcll(m3);
    }
    if (lane == 0) s_cnt[w] = total;
    __syncthreads();

    int start = 0;
#pragma unroll
    for (int i = 0; i < 4; ++i) if (i < w) start += s_cnt[i];
    const int degree = s_cnt[0] + s_cnt[1] + s_cnt[2] + s_cnt[3];
    const int nstore = total < D_MAXN ? total : D_MAXN;
    if (lane < nstore) {
        const int gpos = start + lane;
        if (gpos < D_MAXN) neigh[n * D_MAXN + gpos] = s_idx[w][lane];
    }
    if (t == 0) deg[n] = degree;
}

// ---------------------------------------------------------------------------
// Per-node multi-head attention; K/V combined in one [R, 2E] bf16 buffer
// (cols 0..E-1 = K, E..2E-1 = V). Wave h owns head h; ushort4 loads.
// ---------------------------------------------------------------------------
__global__ __launch_bounds__(256) void attn_kernel(
    const float* __restrict__ Q, const unsigned short* __restrict__ KV,
    const int* __restrict__ neigh, const int* __restrict__ deg,
    unsigned short* __restrict__ attn_out)
{
    const int n    = blockIdx.x;
    const int t    = threadIdx.x;
    const int h    = t >> 6;
    const int lane = t & 63;

    const int degree = deg[n];
    unsigned short* orow = attn_out + (size_t)n * E_DIM;

    if (degree == 0) {
        for (int j = t; j < E_DIM; j += 256) orow[j] = 0;
        return;
    }
    const int dv = degree < D_MAXN ? degree : D_MAXN;

    __shared__ float s_scores[H_HEADS][D_MAXN];
    __shared__ float s_w[H_HEADS][D_MAXN];
    __shared__ int   s_neigh[D_MAXN];

    if (t < dv) s_neigh[t] = neigh[n * D_MAXN + t];
    __syncthreads();

    // q fragment: lane holds contiguous elements h*256 + lane*4 .. +3
    const float4 q = *(const float4*)(Q + (size_t)n * E_DIM + h * DH_DIM + lane * 4);
    const float scale = 0.0625f;  // 1/sqrt(256)

    for (int d = 0; d < dv; ++d) {
        const int r = s_neigh[d];
        const ushort4 kv = *(const ushort4*)(KV + (size_t)r * 2 * E_DIM + h * DH_DIM + lane * 4);
        float s = q.x * bf2f(kv.x) + q.y * bf2f(kv.y) + q.z * bf2f(kv.z) + q.w * bf2f(kv.w);
#pragma unroll
        for (int off = 32; off > 0; off >>= 1) s += __shfl_xor(s, off);
        if (lane == 0) s_scores[h][d] = s * scale;
    }
    __syncthreads();

    {
        float v = (lane < dv) ? s_scores[h][lane] : -3.4e38f;
        float mx = v;
#pragma unroll
        for (int off = 32; off > 0; off >>= 1) mx = fmaxf(mx, __shfl_xor(mx, off));
        float e = (lane < dv) ? __expf(v - mx) : 0.0f;
        float sum = e;
#pragma unroll
        for (int off = 32; off > 0; off >>= 1) sum += __shfl_xor(sum, off);
        if (lane < dv) s_w[h][lane] = e / sum;
    }
    __syncthreads();

    float a0 = 0.f, a1 = 0.f, a2 = 0.f, a3 = 0.f;
    for (int d = 0; d < dv; ++d) {
        const int r = s_neigh[d];
        const float wgt = s_w[h][d];
        const ushort4 vv = *(const ushort4*)(KV + (size_t)r * 2 * E_DIM + E_DIM + h * DH_DIM + lane * 4);
        a0 = fmaf(wgt, bf2f(vv.x), a0);
        a1 = fmaf(wgt, bf2f(vv.y), a1);
        a2 = fmaf(wgt, bf2f(vv.z), a2);
        a3 = fmaf(wgt, bf2f(vv.w), a3);
    }
    ushort4 o;
    o.x = f2bf(a0); o.y = f2bf(a1); o.z = f2bf(a2); o.w = f2bf(a3);
    *(ushort4*)(orow + h * DH_DIM + lane * 4) = o;
}

// ---------------------------------------------------------------------------
extern "C" void kernel_launch(void* const* d_in, const int* in_sizes, int n_in,
                              void* d_out, int out_size, void* d_ws, size_t ws_size,
                              hipStream_t stream)
{
    const float* target  = (const float*)d_in[0];   // [N, E]
    const float* source  = (const float*)d_in[1];   // [R, E]
    const float* adj     = (const float*)d_in[2];   // [N, R]
    const float* W_trans = (const float*)d_in[3];   // [E, E]
    const float* b_trans = (const float*)d_in[4];   // [E]
    const float* in_w    = (const float*)d_in[5];   // [3E, E]
    const float* in_b    = (const float*)d_in[6];   // [3E]
    const float* out_w   = (const float*)d_in[7];   // [E, E]
    const float* out_b   = (const float*)d_in[8];   // [E]
    float* out = (float*)d_out;                     // [N, E] f32

    char* ws = (char*)d_ws;
    unsigned short* src_bf    = (unsigned short*)ws; ws += (size_t)R_SRC * E_DIM * 2;
    unsigned short* wt_bf     = (unsigned short*)ws; ws += (size_t)E_DIM * E_DIM * 2;
    unsigned short* inw_bf    = (unsigned short*)ws; ws += (size_t)3 * E_DIM * E_DIM * 2;
    unsigned short* outw_bf   = (unsigned short*)ws; ws += (size_t)E_DIM * E_DIM * 2;
    unsigned short* tgt_bf    = (unsigned short*)ws; ws += (size_t)N_NODES * E_DIM * 2;
    unsigned short* srcrel_bf = (unsigned short*)ws; ws += (size_t)R_SRC * E_DIM * 2;
    unsigned short* KV_bf     = (unsigned short*)ws; ws += (size_t)R_SRC * 2 * E_DIM * 2;
    float*          Qm        = (float*)ws;          ws += (size_t)N_NODES * E_DIM * 4;
    unsigned short* attn_bf   = (unsigned short*)ws; ws += (size_t)N_NODES * E_DIM * 2;
    int*            neigh     = (int*)ws;            ws += (size_t)N_NODES * D_MAXN * 4;
    int*            deg       = (int*)ws;            ws += (size_t)N_NODES * 4;

    // neighbor lists
    build_neigh<<<N_NODES, 256, 0, stream>>>(adj, neigh, deg);

    // all fp32->bf16 conversions in one dispatch
    {
        ConvArgs a;
        const unsigned sz4[5] = {
            (unsigned)((size_t)R_SRC * E_DIM / 4),
            (unsigned)((size_t)E_DIM * E_DIM / 4),
            (unsigned)((size_t)3 * E_DIM * E_DIM / 4),
            (unsigned)((size_t)E_DIM * E_DIM / 4),
            (unsigned)((size_t)N_NODES * E_DIM / 4)};
        a.s[0] = source;  a.d[0] = src_bf;
        a.s[1] = W_trans; a.d[1] = wt_bf;
        a.s[2] = in_w;    a.d[2] = inw_bf;
        a.s[3] = out_w;   a.d[3] = outw_bf;
        a.s[4] = target;  a.d[4] = tgt_bf;
        a.off[0] = 0;
        for (int i = 0; i < 5; ++i) a.off[i + 1] = a.off[i] + sz4[i];
        f2bf_multi<<<(a.off[5] + 255) / 256, 256, 0, stream>>>(a);
    }

    const size_t EE = (size_t)E_DIM * E_DIM;

    // src_relu = relu(source @ W_trans^T + b_trans)          [R, E] bf16
    gemm_mfma<1, 1, 0><<<dim3(E_DIM / 128, R_SRC / 128), 256, 0, stream>>>(
        src_bf, wt_bf, b_trans, srcrel_bf, R_SRC, E_DIM, E_DIM, nullptr);

    // KV = src_relu @ [Wk;Wv]^T + [bk;bv]                    [R, 2E] bf16
    gemm_mfma<0, 1, 0><<<dim3(2 * E_DIM / 128, R_SRC / 128), 256, 0, stream>>>(
        srcrel_bf, inw_bf + EE, in_b + E_DIM, KV_bf, R_SRC, 2 * E_DIM, E_DIM, nullptr);

    // Q = target @ Wq^T + bq                                 [N, E] f32
    gemm_mfma<0, 0, 0><<<dim3(E_DIM / 128, N_NODES / 128), 256, 0, stream>>>(
        tgt_bf, inw_bf, in_b, Qm, N_NODES, E_DIM, E_DIM, nullptr);

    // attention -> bf16
    attn_kernel<<<N_NODES, 256, 0, stream>>>(Qm, KV_bf, neigh, deg, attn_bf);

    // out = attn_out @ out_w^T + out_b, deg==0 rows zeroed   [N, E] f32
    gemm_mfma<0, 0, 1><<<dim3(E_DIM / 128, N_NODES / 128), 256, 0, stream>>>(
        attn_bf, outw_bf, out_b, out, N_NODES, E_DIM, E_DIM, deg);
}

// Round 5
// 158.781 us; speedup vs baseline: 5.7920x; 1.1554x over previous
//
#include <hip/hip_runtime.h>

#define N_NODES 1024
#define R_SRC   8192
#define E_DIM   1024
#define H_HEADS 4
#define DH_DIM  256
#define D_MAXN  48

typedef __attribute__((ext_vector_type(8))) short short8;
typedef __attribute__((ext_vector_type(4))) float f32x4;

__device__ __forceinline__ unsigned short f2bf(float f) {
    unsigned u = __float_as_uint(f);
    unsigned r = u + 0x7fffu + ((u >> 16) & 1u);   // round-to-nearest-even
    return (unsigned short)(r >> 16);
}
__device__ __forceinline__ float bf2f(unsigned short b) {
    return __uint_as_float(((unsigned)b) << 16);
}
__device__ __forceinline__ void gload16(const void* g, void* l) {
    __builtin_amdgcn_global_load_lds(
        (const __attribute__((address_space(1))) unsigned int*)g,
        (__attribute__((address_space(3))) unsigned int*)l,
        16, 0, 0);
}

// ---------------------------------------------------------------------------
// Generic bf16 MFMA NT GEMM body. Tile BM x BN, BK=32, 256 threads = 4 waves
// arranged WR x WC; per-wave FM x FN 16x16x32 fragments. LDS linear:
// A tile [BM][32] at S[0], B tile [BN][32] at S[BM*32].
// ---------------------------------------------------------------------------
template<int BM, int BN, int WR, int WC>
__device__ __forceinline__ void gemm_body(
    const unsigned short* __restrict__ A, const unsigned short* __restrict__ W,
    const float* __restrict__ bias, void* __restrict__ Cout,
    int N, int K, int m0, int n0,
    int relu, int outbf, const int* __restrict__ rowmask)
{
    constexpr int FM = BM / WR / 16;
    constexpr int FN = BN / WC / 16;
    constexpr int NCHUNK = (BM + BN) / 64;   // 16B chunks per thread per K-step

    __shared__ __align__(16) unsigned short S[(BM + BN) * 32];

    const int t = threadIdx.x;
    const int w = t >> 6, l = t & 63;
    const int wrow = (w / WC) * (FM * 16);
    const int wcol = (w % WC) * (FN * 16);
    const int lr = l & 15;
    const int kg = (l >> 4) * 8;

    f32x4 acc[FM][FN] = {};

    const unsigned short* gp[NCHUNK];
    unsigned short* lp[NCHUNK];
#pragma unroll
    for (int i = 0; i < NCHUNK; ++i) {
        const int c = t + 256 * i;
        if (c < BM * 4) {
            gp[i] = A + (size_t)(m0 + (c >> 2)) * K + (c & 3) * 8;
            lp[i] = &S[c * 8];
        } else {
            const int c2 = c - BM * 4;
            gp[i] = W + (size_t)(n0 + (c2 >> 2)) * K + (c2 & 3) * 8;
            lp[i] = &S[BM * 32 + c2 * 8];
        }
    }

    for (int k0 = 0; k0 < K; k0 += 32) {
#pragma unroll
        for (int i = 0; i < NCHUNK; ++i) gload16(gp[i] + k0, lp[i]);
        __syncthreads();   // compiler drains vmcnt(0) before barrier

        short8 af[FM], bw[FN];
#pragma unroll
        for (int i = 0; i < FM; ++i)
            af[i] = *(const short8*)&S[(wrow + i * 16 + lr) * 32 + kg];
#pragma unroll
        for (int j = 0; j < FN; ++j)
            bw[j] = *(const short8*)&S[BM * 32 + (wcol + j * 16 + lr) * 32 + kg];
#pragma unroll
        for (int i = 0; i < FM; ++i)
#pragma unroll
            for (int j = 0; j < FN; ++j)
                acc[i][j] = __builtin_amdgcn_mfma_f32_16x16x32_bf16(
                    af[i], bw[j], acc[i][j], 0, 0, 0);
        __syncthreads();
    }

    // epilogue: C/D layout col = lane&15, row = (lane>>4)*4 + q
#pragma unroll
    for (int j = 0; j < FN; ++j) {
        const int c = n0 + wcol + j * 16 + (l & 15);
        const float bv = bias[c];
#pragma unroll
        for (int i = 0; i < FM; ++i) {
            const int rbase = m0 + wrow + i * 16 + (l >> 4) * 4;
#pragma unroll
            for (int q = 0; q < 4; ++q) {
                const int r = rbase + q;
                float x = acc[i][j][q] + bv;
                if (relu) x = fmaxf(x, 0.0f);
                if (rowmask) { if (rowmask[r] == 0) x = 0.0f; }
                if (outbf) ((unsigned short*)Cout)[(size_t)r * N + c] = f2bf(x);
                else       ((float*)Cout)[(size_t)r * N + c] = x;
            }
        }
    }
}

template<int BM, int BN, int WR, int WC>
__global__ __launch_bounds__(256) void gemm_k(
    const unsigned short* __restrict__ A, const unsigned short* __restrict__ W,
    const float* __restrict__ bias, void* __restrict__ Cout,
    int N, int K, int relu, int outbf, const int* __restrict__ rowmask)
{
    gemm_body<BM, BN, WR, WC>(A, W, bias, Cout, N, K,
                              blockIdx.y * BM, blockIdx.x * BN,
                              relu, outbf, rowmask);
}

// ---------------------------------------------------------------------------
// Dual-descriptor 128x128 GEMM: blocks [0,split) run desc0, rest desc1.
// Used to run the KV GEMM and the small Q GEMM in one dispatch.
// ---------------------------------------------------------------------------
struct GemmDesc {
    const unsigned short* A;
    const unsigned short* W;
    const float* bias;
    void* C;
    int N, K, outbf, nbx;
};

__global__ __launch_bounds__(256) void gemm_dual(GemmDesc d0, GemmDesc d1, int split)
{
    const int bid = blockIdx.x;
    GemmDesc d;
    int q;
    if (bid < split) { d = d0; q = bid; }
    else             { d = d1; q = bid - split; }
    const int m0 = (q / d.nbx) * 128;
    const int n0 = (q % d.nbx) * 128;
    gemm_body<128, 128, 2, 2>(d.A, d.W, d.bias, d.C, d.N, d.K, m0, n0,
                              0, d.outbf, nullptr);
}

// ---------------------------------------------------------------------------
// Fused pre-pass: blocks [0, N_NODES) build neighbor lists; remaining blocks
// do the fp32->bf16 conversions of all GEMM operands.
// ---------------------------------------------------------------------------
struct ConvArgs {
    const float* s[5];
    unsigned short* d[5];
    unsigned off[6];   // prefix offsets in float4 units; off[5] = total
};

__global__ __launch_bounds__(256) void pre_kernel(
    const float* __restrict__ adj, int* __restrict__ neigh, int* __restrict__ deg,
    ConvArgs a)
{
    const int t = threadIdx.x;

    if (blockIdx.x >= N_NODES) {
        // ---- conversion part ----
        unsigned i = (blockIdx.x - N_NODES) * 256 + t;
        if (i >= a.off[5]) return;
        int seg = 0;
#pragma unroll
        for (int s = 1; s < 5; ++s) seg += (i >= a.off[s]);
        unsigned j = i - a.off[seg];
        float4 v = ((const float4*)a.s[seg])[j];
        ushort4 o;
        o.x = f2bf(v.x); o.y = f2bf(v.y); o.z = f2bf(v.z); o.w = f2bf(v.w);
        ((ushort4*)a.d[seg])[j] = o;
        return;
    }

    // ---- neighbor-list part: 4 waves, wave w owns columns [w*2048,(w+1)*2048)
    const int n    = blockIdx.x;
    const int w    = t >> 6;
    const int lane = t & 63;
    const float* row = adj + (size_t)n * R_SRC;

    __shared__ int s_cnt[4];
    __shared__ int s_idx[4][D_MAXN];

    const int seg0 = w * (R_SRC / 4);
    const unsigned long long lower = (1ULL << lane) - 1ULL;
    int total = 0;

    for (int base = seg0; base < seg0 + R_SRC / 4; base += 256) {
        const float v0 = row[base + lane];
        const float v1 = row[base + 64 + lane];
        const float v2 = row[base + 128 + lane];
        const float v3 = row[base + 192 + lane];
        const unsigned long long m0 = __ballot(v0 != 0.0f);
        const unsigned long long m1 = __ballot(v1 != 0.0f);
        const unsigned long long m2 = __ballot(v2 != 0.0f);
        const unsigned long long m3 = __ballot(v3 != 0.0f);
        int p;
        p = total + __popcll(m0 & lower);
        if (v0 != 0.0f && p < D_MAXN) s_idx[w][p] = base + lane;
        total += __popcll(m0);
        p = total + __popcll(m1 & lower);
        if (v1 != 0.0f && p < D_MAXN) s_idx[w][p] = base + 64 + lane;
        total += __popcll(m1);
        p = total + __popcll(m2 & lower);
        if (v2 != 0.0f && p < D_MAXN) s_idx[w][p] = base + 128 + lane;
        total += __popcll(m2);
        p = total + __popcll(m3 & lower);
        if (v3 != 0.0f && p < D_MAXN) s_idx[w][p] = base + 192 + lane;
        total += __popcll(m3);
    }
    if (lane == 0) s_cnt[w] = total;
    __syncthreads();

    int start = 0;
#pragma unroll
    for (int i = 0; i < 4; ++i) if (i < w) start += s_cnt[i];
    const int degree = s_cnt[0] + s_cnt[1] + s_cnt[2] + s_cnt[3];
    const int nstore = total < D_MAXN ? total : D_MAXN;
    if (lane < nstore) {
        const int gpos = start + lane;
        if (gpos < D_MAXN) neigh[n * D_MAXN + gpos] = s_idx[w][lane];
    }
    if (t == 0) deg[n] = degree;
}

// ---------------------------------------------------------------------------
// Per-node multi-head attention; K/V combined in one [R, 2E] bf16 buffer.
// ---------------------------------------------------------------------------
__global__ __launch_bounds__(256) void attn_kernel(
    const float* __restrict__ Q, const unsigned short* __restrict__ KV,
    const int* __restrict__ neigh, const int* __restrict__ deg,
    unsigned short* __restrict__ attn_out)
{
    const int n    = blockIdx.x;
    const int t    = threadIdx.x;
    const int h    = t >> 6;
    const int lane = t & 63;

    const int degree = deg[n];
    unsigned short* orow = attn_out + (size_t)n * E_DIM;

    if (degree == 0) {
        for (int j = t; j < E_DIM; j += 256) orow[j] = 0;
        return;
    }
    const int dv = degree < D_MAXN ? degree : D_MAXN;

    __shared__ float s_scores[H_HEADS][D_MAXN];
    __shared__ float s_w[H_HEADS][D_MAXN];
    __shared__ int   s_neigh[D_MAXN];

    if (t < dv) s_neigh[t] = neigh[n * D_MAXN + t];
    __syncthreads();

    const float4 q = *(const float4*)(Q + (size_t)n * E_DIM + h * DH_DIM + lane * 4);
    const float scale = 0.0625f;  // 1/sqrt(256)

    for (int d = 0; d < dv; ++d) {
        const int r = s_neigh[d];
        const ushort4 kv = *(const ushort4*)(KV + (size_t)r * 2 * E_DIM + h * DH_DIM + lane * 4);
        float s = q.x * bf2f(kv.x) + q.y * bf2f(kv.y) + q.z * bf2f(kv.z) + q.w * bf2f(kv.w);
#pragma unroll
        for (int off = 32; off > 0; off >>= 1) s += __shfl_xor(s, off);
        if (lane == 0) s_scores[h][d] = s * scale;
    }
    __syncthreads();

    {
        float v = (lane < dv) ? s_scores[h][lane] : -3.4e38f;
        float mx = v;
#pragma unroll
        for (int off = 32; off > 0; off >>= 1) mx = fmaxf(mx, __shfl_xor(mx, off));
        float e = (lane < dv) ? __expf(v - mx) : 0.0f;
        float sum = e;
#pragma unroll
        for (int off = 32; off > 0; off >>= 1) sum += __shfl_xor(sum, off);
        if (lane < dv) s_w[h][lane] = e / sum;
    }
    __syncthreads();

    float a0 = 0.f, a1 = 0.f, a2 = 0.f, a3 = 0.f;
    for (int d = 0; d < dv; ++d) {
        const int r = s_neigh[d];
        const float wgt = s_w[h][d];
        const ushort4 vv = *(const ushort4*)(KV + (size_t)r * 2 * E_DIM + E_DIM + h * DH_DIM + lane * 4);
        a0 = fmaf(wgt, bf2f(vv.x), a0);
        a1 = fmaf(wgt, bf2f(vv.y), a1);
        a2 = fmaf(wgt, bf2f(vv.z), a2);
        a3 = fmaf(wgt, bf2f(vv.w), a3);
    }
    ushort4 o;
    o.x = f2bf(a0); o.y = f2bf(a1); o.z = f2bf(a2); o.w = f2bf(a3);
    *(ushort4*)(orow + h * DH_DIM + lane * 4) = o;
}

// ---------------------------------------------------------------------------
extern "C" void kernel_launch(void* const* d_in, const int* in_sizes, int n_in,
                              void* d_out, int out_size, void* d_ws, size_t ws_size,
                              hipStream_t stream)
{
    const float* target  = (const float*)d_in[0];   // [N, E]
    const float* source  = (const float*)d_in[1];   // [R, E]
    const float* adj     = (const float*)d_in[2];   // [N, R]
    const float* W_trans = (const float*)d_in[3];   // [E, E]
    const float* b_trans = (const float*)d_in[4];   // [E]
    const float* in_w    = (const float*)d_in[5];   // [3E, E]
    const float* in_b    = (const float*)d_in[6];   // [3E]
    const float* out_w   = (const float*)d_in[7];   // [E, E]
    const float* out_b   = (const float*)d_in[8];   // [E]
    float* out = (float*)d_out;                     // [N, E] f32

    char* ws = (char*)d_ws;
    unsigned short* src_bf    = (unsigned short*)ws; ws += (size_t)R_SRC * E_DIM * 2;
    unsigned short* wt_bf     = (unsigned short*)ws; ws += (size_t)E_DIM * E_DIM * 2;
    unsigned short* inw_bf    = (unsigned short*)ws; ws += (size_t)3 * E_DIM * E_DIM * 2;
    unsigned short* outw_bf   = (unsigned short*)ws; ws += (size_t)E_DIM * E_DIM * 2;
    unsigned short* tgt_bf    = (unsigned short*)ws; ws += (size_t)N_NODES * E_DIM * 2;
    unsigned short* srcrel_bf = (unsigned short*)ws; ws += (size_t)R_SRC * E_DIM * 2;
    unsigned short* KV_bf     = (unsigned short*)ws; ws += (size_t)R_SRC * 2 * E_DIM * 2;
    float*          Qm        = (float*)ws;          ws += (size_t)N_NODES * E_DIM * 4;
    unsigned short* attn_bf   = (unsigned short*)ws; ws += (size_t)N_NODES * E_DIM * 2;
    int*            neigh     = (int*)ws;            ws += (size_t)N_NODES * D_MAXN * 4;
    int*            deg       = (int*)ws;            ws += (size_t)N_NODES * 4;

    // 1) fused pre-pass: neighbor lists + all fp32->bf16 conversions
    {
        ConvArgs a;
        const unsigned sz4[5] = {
            (unsigned)((size_t)R_SRC * E_DIM / 4),
            (unsigned)((size_t)E_DIM * E_DIM / 4),
            (unsigned)((size_t)3 * E_DIM * E_DIM / 4),
            (unsigned)((size_t)E_DIM * E_DIM / 4),
            (unsigned)((size_t)N_NODES * E_DIM / 4)};
        a.s[0] = source;  a.d[0] = src_bf;
        a.s[1] = W_trans; a.d[1] = wt_bf;
        a.s[2] = in_w;    a.d[2] = inw_bf;
        a.s[3] = out_w;   a.d[3] = outw_bf;
        a.s[4] = target;  a.d[4] = tgt_bf;
        a.off[0] = 0;
        for (int i = 0; i < 5; ++i) a.off[i + 1] = a.off[i] + sz4[i];
        const int nconv = (a.off[5] + 255) / 256;
        pre_kernel<<<N_NODES + nconv, 256, 0, stream>>>(adj, neigh, deg, a);
    }

    const size_t EE = (size_t)E_DIM * E_DIM;

    // 2) src_relu = relu(source @ W_trans^T + b_trans)  [R, E] bf16
    //    128x64 tile -> 1024 blocks (4 blocks/CU)
    gemm_k<128, 64, 4, 1><<<dim3(E_DIM / 64, R_SRC / 128), 256, 0, stream>>>(
        src_bf, wt_bf, b_trans, srcrel_bf, E_DIM, E_DIM, 1, 1, nullptr);

    // 3) fused: KV = src_relu @ [Wk;Wv]^T + [bk;bv]  [R, 2E] bf16  (1024 blocks)
    //         + Q = target @ Wq^T + bq               [N, E]  f32   (64 blocks)
    {
        GemmDesc dkv, dq;
        dkv.A = srcrel_bf; dkv.W = inw_bf + EE; dkv.bias = in_b + E_DIM;
        dkv.C = KV_bf; dkv.N = 2 * E_DIM; dkv.K = E_DIM; dkv.outbf = 1;
        dkv.nbx = 2 * E_DIM / 128;
        dq.A = tgt_bf; dq.W = inw_bf; dq.bias = in_b;
        dq.C = Qm; dq.N = E_DIM; dq.K = E_DIM; dq.outbf = 0;
        dq.nbx = E_DIM / 128;
        const int kvblocks = (2 * E_DIM / 128) * (R_SRC / 128);
        const int qblocks  = (E_DIM / 128) * (N_NODES / 128);
        gemm_dual<<<kvblocks + qblocks, 256, 0, stream>>>(dkv, dq, kvblocks);
    }

    // 4) attention -> bf16
    attn_kernel<<<N_NODES, 256, 0, stream>>>(Qm, KV_bf, neigh, deg, attn_bf);

    // 5) out = attn_out @ out_w^T + out_b, deg==0 rows zeroed  [N, E] f32
    //    64x64 tile -> 256 blocks
    gemm_k<64, 64, 2, 2><<<dim3(E_DIM / 64, N_NODES / 64), 256, 0, stream>>>(
        attn_bf, outw_bf, out_b, out, E_DIM, E_DIM, 0, 0, deg);
}

// Round 6
// 145.425 us; speedup vs baseline: 6.3239x; 1.0918x over previous
//
#include <hip/hip_runtime.h>

#define N_NODES 1024
#define R_SRC   8192
#define E_DIM   1024
#define H_HEADS 4
#define DH_DIM  256
#define D_MAXN  48

typedef __attribute__((ext_vector_type(8))) short short8;
typedef __attribute__((ext_vector_type(4))) float f32x4;

__device__ __forceinline__ unsigned short f2bf(float f) {
    unsigned u = __float_as_uint(f);
    unsigned r = u + 0x7fffu + ((u >> 16) & 1u);   // round-to-nearest-even
    return (unsigned short)(r >> 16);
}
__device__ __forceinline__ float bf2f(unsigned short b) {
    return __uint_as_float(((unsigned)b) << 16);
}
__device__ __forceinline__ void gload16(const void* g, void* l) {
    __builtin_amdgcn_global_load_lds(
        (const __attribute__((address_space(1))) unsigned int*)g,
        (__attribute__((address_space(3))) unsigned int*)l,
        16, 0, 0);
}

// ===========================================================================
// 256x256 deep-pipelined bf16 MFMA NT GEMM (8-phase-family structure):
//   BK=64, 512 threads = 8 waves (2M x 4N), per-wave 128x64 output
//   (8x4 16x16x32 fragments), double-buffered 128 KB LDS,
//   XOR-swizzled LDS (chunk ^= row&7; pre-swizzled global source so the
//   linear global_load_lds dest + swizzled ds_read agree  [rule #21]),
//   counted s_waitcnt vmcnt(8) (never 0 mid-loop) + raw s_barrier [T3/T4],
//   s_setprio around MFMA clusters [T5].
// Dual-descriptor grid: blocks [0,split) use d0, rest d1.
// ===========================================================================
struct GD256 {
    const unsigned short* A;   // [M, K] bf16, K-contiguous
    const unsigned short* B;   // [N, K] bf16, K-contiguous
    const float* bias;         // [N]
    void* C;                   // [M, N] bf16 or f32
    int N, K, nbx, relu, outbf;
    const int* rowmask;        // optional: rows with mask==0 forced to 0
};

__global__ __launch_bounds__(512) void gemm256(GD256 d0, GD256 d1, int split)
{
    __shared__ __align__(16) unsigned short lds[2][2][256 * 64];  // 128 KiB

    int bid = blockIdx.x;
    const int nwg = gridDim.x;                 // callers keep nwg % 8 == 0
    bid = (bid & 7) * (nwg >> 3) + (bid >> 3); // XCD-aware swizzle [T1]

    GD256 d; int q;
    if (bid < split) { d = d0; q = bid; }
    else             { d = d1; q = bid - split; }
    const int m0 = (q / d.nbx) * 256;
    const int n0 = (q % d.nbx) * 256;
    const int K  = d.K;

    const int t = threadIdx.x;                 // 0..511
    const int w = t >> 6, l = t & 63;
    const int wm = w >> 2, wn = w & 3;         // 2 x 4 wave grid

    // ---- staging addresses: thread t stages LDS 16B-chunk (i*512+t).
    // LDS dest is linear (wave-uniform base + lane*16). The k-chunk of the
    // GLOBAL source is pre-swizzled (kc ^ row&7) so that the swizzled
    // ds_read below sees data at chunk g ^ (row&7)  ==  global chunk g.
    const int trow = t >> 3, tkc = t & 7;
    const int tswz = tkc ^ (trow & 7);
    const unsigned short* gA[4];
    const unsigned short* gB[4];
#pragma unroll
    for (int i = 0; i < 4; ++i) {
        gA[i] = d.A + (size_t)(m0 + i * 64 + trow) * K + tswz * 8;
        gB[i] = d.B + (size_t)(n0 + i * 64 + trow) * K + tswz * 8;
    }

    f32x4 acc[8][4] = {};

    auto STAGE = [&](int c, int kt) {
        const int ko = kt * 64;
#pragma unroll
        for (int i = 0; i < 4; ++i)
            gload16(gA[i] + ko, &lds[c][0][(i * 512 + t) * 8]);
#pragma unroll
        for (int i = 0; i < 4; ++i)
            gload16(gB[i] + ko, &lds[c][1][(i * 512 + t) * 8]);
    };

    const int nt = K / 64;
    STAGE(0, 0);
    STAGE(1, 1);
    asm volatile("s_waitcnt vmcnt(8)" ::: "memory");  // tile 0 landed
    __builtin_amdgcn_s_barrier();

    // ---- ds_read fragment addressing (swizzled)
    const int lr = l & 15, hi = l >> 4;
    const int rsw = l & 7;                       // == row & 7 for our rows
    const int cs0 = ((0 + hi) ^ rsw) * 8;        // ks=0 chunk
    const int cs1 = ((4 + hi) ^ rsw) * 8;        // ks=1 chunk
    const int abase = (wm * 128 + lr) * 64;
    const int bbase = (wn * 64  + lr) * 64;

    for (int kt = 0; kt < nt; ++kt) {
        const int cur = kt & 1;
        const unsigned short* As = &lds[cur][0][0];
        const unsigned short* Bs = &lds[cur][1][0];

        short8 av[4][2], bv[4][2];
        // phase A: A-frags 0..3 + all B-frags -> 16 MFMA x2ks
#pragma unroll
        for (int fi = 0; fi < 4; ++fi) {
            av[fi][0] = *(const short8*)&As[abase + fi * 1024 + cs0];
            av[fi][1] = *(const short8*)&As[abase + fi * 1024 + cs1];
        }
#pragma unroll
        for (int fj = 0; fj < 4; ++fj) {
            bv[fj][0] = *(const short8*)&Bs[bbase + fj * 1024 + cs0];
            bv[fj][1] = *(const short8*)&Bs[bbase + fj * 1024 + cs1];
        }
        __builtin_amdgcn_s_setprio(1);
#pragma unroll
        for (int ks = 0; ks < 2; ++ks)
#pragma unroll
            for (int fi = 0; fi < 4; ++fi)
#pragma unroll
                for (int fj = 0; fj < 4; ++fj)
                    acc[fi][fj] = __builtin_amdgcn_mfma_f32_16x16x32_bf16(
                        av[fi][ks], bv[fj][ks], acc[fi][fj], 0, 0, 0);
        __builtin_amdgcn_s_setprio(0);

        // phase B: A-frags 4..7 (reuse bv)
#pragma unroll
        for (int fi = 0; fi < 4; ++fi) {
            av[fi][0] = *(const short8*)&As[abase + (fi + 4) * 1024 + cs0];
            av[fi][1] = *(const short8*)&As[abase + (fi + 4) * 1024 + cs1];
        }
        __builtin_amdgcn_s_setprio(1);
#pragma unroll
        for (int ks = 0; ks < 2; ++ks)
#pragma unroll
            for (int fi = 0; fi < 4; ++fi)
#pragma unroll
                for (int fj = 0; fj < 4; ++fj)
                    acc[fi + 4][fj] = __builtin_amdgcn_mfma_f32_16x16x32_bf16(
                        av[fi][ks], bv[fj][ks], acc[fi + 4][fj], 0, 0, 0);
        __builtin_amdgcn_s_setprio(0);

        asm volatile("" ::: "memory");
        __builtin_amdgcn_s_barrier();            // all waves done reading buf[cur]
        if (kt + 2 < nt) {
            STAGE(cur, kt + 2);                  // refill just-freed buffer
            asm volatile("s_waitcnt vmcnt(8)" ::: "memory");  // tile kt+1 landed
        } else {
            asm volatile("s_waitcnt vmcnt(0)" ::: "memory");  // drain tail
        }
        __builtin_amdgcn_s_barrier();            // tile kt+1 visible to all waves
    }

    // ---- epilogue: C/D layout col = lane&15, row = (lane>>4)*4 + qq
#pragma unroll
    for (int fj = 0; fj < 4; ++fj) {
        const int c = n0 + wn * 64 + fj * 16 + lr;
        const float bvs = d.bias[c];
#pragma unroll
        for (int fi = 0; fi < 8; ++fi) {
            const int rb = m0 + wm * 128 + fi * 16 + hi * 4;
#pragma unroll
            for (int qq = 0; qq < 4; ++qq) {
                const int r = rb + qq;
                float x = acc[fi][fj][qq] + bvs;
                if (d.relu) x = fmaxf(x, 0.0f);
                if (d.rowmask && d.rowmask[r] == 0) x = 0.0f;
                if (d.outbf) ((unsigned short*)d.C)[(size_t)r * d.N + c] = f2bf(x);
                else         ((float*)d.C)[(size_t)r * d.N + c] = x;
            }
        }
    }
}

// ===========================================================================
// Small-tile fp32-out GEMM (kept for the final out-projection, 256 blocks)
// ===========================================================================
template<int BM, int BN, int WR, int WC>
__global__ __launch_bounds__(256) void gemm_k(
    const unsigned short* __restrict__ A, const unsigned short* __restrict__ W,
    const float* __restrict__ bias, void* __restrict__ Cout,
    int N, int K, int relu, int outbf, const int* __restrict__ rowmask)
{
    constexpr int FM = BM / WR / 16;
    constexpr int FN = BN / WC / 16;
    constexpr int NCHUNK = (BM + BN) / 64;

    __shared__ __align__(16) unsigned short S[(BM + BN) * 32];

    const int t = threadIdx.x;
    const int m0 = blockIdx.y * BM;
    const int n0 = blockIdx.x * BN;
    const int w = t >> 6, l = t & 63;
    const int wrow = (w / WC) * (FM * 16);
    const int wcol = (w % WC) * (FN * 16);
    const int lr = l & 15;
    const int kg = (l >> 4) * 8;

    f32x4 acc[FM][FN] = {};

    const unsigned short* gp[NCHUNK];
    unsigned short* lp[NCHUNK];
#pragma unroll
    for (int i = 0; i < NCHUNK; ++i) {
        const int c = t + 256 * i;
        if (c < BM * 4) {
            gp[i] = A + (size_t)(m0 + (c >> 2)) * K + (c & 3) * 8;
            lp[i] = &S[c * 8];
        } else {
            const int c2 = c - BM * 4;
            gp[i] = W + (size_t)(n0 + (c2 >> 2)) * K + (c2 & 3) * 8;
            lp[i] = &S[BM * 32 + c2 * 8];
        }
    }

    for (int k0 = 0; k0 < K; k0 += 32) {
#pragma unroll
        for (int i = 0; i < NCHUNK; ++i) gload16(gp[i] + k0, lp[i]);
        __syncthreads();

        short8 af[FM], bw[FN];
#pragma unroll
        for (int i = 0; i < FM; ++i)
            af[i] = *(const short8*)&S[(wrow + i * 16 + lr) * 32 + kg];
#pragma unroll
        for (int j = 0; j < FN; ++j)
            bw[j] = *(const short8*)&S[BM * 32 + (wcol + j * 16 + lr) * 32 + kg];
#pragma unroll
        for (int i = 0; i < FM; ++i)
#pragma unroll
            for (int j = 0; j < FN; ++j)
                acc[i][j] = __builtin_amdgcn_mfma_f32_16x16x32_bf16(
                    af[i], bw[j], acc[i][j], 0, 0, 0);
        __syncthreads();
    }

#pragma unroll
    for (int j = 0; j < FN; ++j) {
        const int c = n0 + wcol + j * 16 + (l & 15);
        const float bv = bias[c];
#pragma unroll
        for (int i = 0; i < FM; ++i) {
            const int rbase = m0 + wrow + i * 16 + (l >> 4) * 4;
#pragma unroll
            for (int qq = 0; qq < 4; ++qq) {
                const int r = rbase + qq;
                float x = acc[i][j][qq] + bv;
                if (relu) x = fmaxf(x, 0.0f);
                if (rowmask) { if (rowmask[r] == 0) x = 0.0f; }
                if (outbf) ((unsigned short*)Cout)[(size_t)r * N + c] = f2bf(x);
                else       ((float*)Cout)[(size_t)r * N + c] = x;
            }
        }
    }
}

// ---------------------------------------------------------------------------
// Fused pre-pass: blocks [0, N_NODES) build neighbor lists; remaining blocks
// do the fp32->bf16 conversions of all GEMM operands.
// ---------------------------------------------------------------------------
struct ConvArgs {
    const float* s[5];
    unsigned short* d[5];
    unsigned off[6];
};

__global__ __launch_bounds__(256) void pre_kernel(
    const float* __restrict__ adj, int* __restrict__ neigh, int* __restrict__ deg,
    ConvArgs a)
{
    const int t = threadIdx.x;

    if (blockIdx.x >= N_NODES) {
        unsigned i = (blockIdx.x - N_NODES) * 256 + t;
        if (i >= a.off[5]) return;
        int seg = 0;
#pragma unroll
        for (int s = 1; s < 5; ++s) seg += (i >= a.off[s]);
        unsigned j = i - a.off[seg];
        float4 v = ((const float4*)a.s[seg])[j];
        ushort4 o;
        o.x = f2bf(v.x); o.y = f2bf(v.y); o.z = f2bf(v.z); o.w = f2bf(v.w);
        ((ushort4*)a.d[seg])[j] = o;
        return;
    }

    const int n    = blockIdx.x;
    const int w    = t >> 6;
    const int lane = t & 63;
    const float* row = adj + (size_t)n * R_SRC;

    __shared__ int s_cnt[4];
    __shared__ int s_idx[4][D_MAXN];

    const int seg0 = w * (R_SRC / 4);
    const unsigned long long lower = (1ULL << lane) - 1ULL;
    int total = 0;

    for (int base = seg0; base < seg0 + R_SRC / 4; base += 256) {
        const float v0 = row[base + lane];
        const float v1 = row[base + 64 + lane];
        const float v2 = row[base + 128 + lane];
        const float v3 = row[base + 192 + lane];
        const unsigned long long m0 = __ballot(v0 != 0.0f);
        const unsigned long long m1 = __ballot(v1 != 0.0f);
        const unsigned long long m2 = __ballot(v2 != 0.0f);
        const unsigned long long m3 = __ballot(v3 != 0.0f);
        int p;
        p = total + __popcll(m0 & lower);
        if (v0 != 0.0f && p < D_MAXN) s_idx[w][p] = base + lane;
        total += __popcll(m0);
        p = total + __popcll(m1 & lower);
        if (v1 != 0.0f && p < D_MAXN) s_idx[w][p] = base + 64 + lane;
        total += __popcll(m1);
        p = total + __popcll(m2 & lower);
        if (v2 != 0.0f && p < D_MAXN) s_idx[w][p] = base + 128 + lane;
        total += __popcll(m2);
        p = total + __popcll(m3 & lower);
        if (v3 != 0.0f && p < D_MAXN) s_idx[w][p] = base + 192 + lane;
        total += __popcll(m3);
    }
    if (lane == 0) s_cnt[w] = total;
    __syncthreads();

    int start = 0;
#pragma unroll
    for (int i = 0; i < 4; ++i) if (i < w) start += s_cnt[i];
    const int degree = s_cnt[0] + s_cnt[1] + s_cnt[2] + s_cnt[3];
    const int nstore = total < D_MAXN ? total : D_MAXN;
    if (lane < nstore) {
        const int gpos = start + lane;
        if (gpos < D_MAXN) neigh[n * D_MAXN + gpos] = s_idx[w][lane];
    }
    if (t == 0) deg[n] = degree;
}

// ---------------------------------------------------------------------------
// Per-node multi-head attention; K/V combined in one [R, 2E] bf16 buffer.
// ---------------------------------------------------------------------------
__global__ __launch_bounds__(256) void attn_kernel(
    const float* __restrict__ Q, const unsigned short* __restrict__ KV,
    const int* __restrict__ neigh, const int* __restrict__ deg,
    unsigned short* __restrict__ attn_out)
{
    const int n    = blockIdx.x;
    const int t    = threadIdx.x;
    const int h    = t >> 6;
    const int lane = t & 63;

    const int degree = deg[n];
    unsigned short* orow = attn_out + (size_t)n * E_DIM;

    if (degree == 0) {
        for (int j = t; j < E_DIM; j += 256) orow[j] = 0;
        return;
    }
    const int dv = degree < D_MAXN ? degree : D_MAXN;

    __shared__ float s_scores[H_HEADS][D_MAXN];
    __shared__ float s_w[H_HEADS][D_MAXN];
    __shared__ int   s_neigh[D_MAXN];

    if (t < dv) s_neigh[t] = neigh[n * D_MAXN + t];
    __syncthreads();

    const float4 qv = *(const float4*)(Q + (size_t)n * E_DIM + h * DH_DIM + lane * 4);
    const float scale = 0.0625f;  // 1/sqrt(256)

    for (int d = 0; d < dv; ++d) {
        const int r = s_neigh[d];
        const ushort4 kv = *(const ushort4*)(KV + (size_t)r * 2 * E_DIM + h * DH_DIM + lane * 4);
        float s = qv.x * bf2f(kv.x) + qv.y * bf2f(kv.y) + qv.z * bf2f(kv.z) + qv.w * bf2f(kv.w);
#pragma unroll
        for (int off = 32; off > 0; off >>= 1) s += __shfl_xor(s, off);
        if (lane == 0) s_scores[h][d] = s * scale;
    }
    __syncthreads();

    {
        float v = (lane < dv) ? s_scores[h][lane] : -3.4e38f;
        float mx = v;
#pragma unroll
        for (int off = 32; off > 0; off >>= 1) mx = fmaxf(mx, __shfl_xor(mx, off));
        float e = (lane < dv) ? __expf(v - mx) : 0.0f;
        float sum = e;
#pragma unroll
        for (int off = 32; off > 0; off >>= 1) sum += __shfl_xor(sum, off);
        if (lane < dv) s_w[h][lane] = e / sum;
    }
    __syncthreads();

    float a0 = 0.f, a1 = 0.f, a2 = 0.f, a3 = 0.f;
    for (int d = 0; d < dv; ++d) {
        const int r = s_neigh[d];
        const float wgt = s_w[h][d];
        const ushort4 vv = *(const ushort4*)(KV + (size_t)r * 2 * E_DIM + E_DIM + h * DH_DIM + lane * 4);
        a0 = fmaf(wgt, bf2f(vv.x), a0);
        a1 = fmaf(wgt, bf2f(vv.y), a1);
        a2 = fmaf(wgt, bf2f(vv.z), a2);
        a3 = fmaf(wgt, bf2f(vv.w), a3);
    }
    ushort4 o;
    o.x = f2bf(a0); o.y = f2bf(a1); o.z = f2bf(a2); o.w = f2bf(a3);
    *(ushort4*)(orow + h * DH_DIM + lane * 4) = o;
}

// ---------------------------------------------------------------------------
extern "C" void kernel_launch(void* const* d_in, const int* in_sizes, int n_in,
                              void* d_out, int out_size, void* d_ws, size_t ws_size,
                              hipStream_t stream)
{
    const float* target  = (const float*)d_in[0];   // [N, E]
    const float* source  = (const float*)d_in[1];   // [R, E]
    const float* adj     = (const float*)d_in[2];   // [N, R]
    const float* W_trans = (const float*)d_in[3];   // [E, E]
    const float* b_trans = (const float*)d_in[4];   // [E]
    const float* in_w    = (const float*)d_in[5];   // [3E, E]
    const float* in_b    = (const float*)d_in[6];   // [3E]
    const float* out_w   = (const float*)d_in[7];   // [E, E]
    const float* out_b   = (const float*)d_in[8];   // [E]
    float* out = (float*)d_out;                     // [N, E] f32

    char* ws = (char*)d_ws;
    unsigned short* src_bf    = (unsigned short*)ws; ws += (size_t)R_SRC * E_DIM * 2;
    unsigned short* wt_bf     = (unsigned short*)ws; ws += (size_t)E_DIM * E_DIM * 2;
    unsigned short* inw_bf    = (unsigned short*)ws; ws += (size_t)3 * E_DIM * E_DIM * 2;
    unsigned short* outw_bf   = (unsigned short*)ws; ws += (size_t)E_DIM * E_DIM * 2;
    unsigned short* tgt_bf    = (unsigned short*)ws; ws += (size_t)N_NODES * E_DIM * 2;
    unsigned short* srcrel_bf = (unsigned short*)ws; ws += (size_t)R_SRC * E_DIM * 2;
    unsigned short* KV_bf     = (unsigned short*)ws; ws += (size_t)R_SRC * 2 * E_DIM * 2;
    float*          Qm        = (float*)ws;          ws += (size_t)N_NODES * E_DIM * 4;
    unsigned short* attn_bf   = (unsigned short*)ws; ws += (size_t)N_NODES * E_DIM * 2;
    int*            neigh     = (int*)ws;            ws += (size_t)N_NODES * D_MAXN * 4;
    int*            deg       = (int*)ws;            ws += (size_t)N_NODES * 4;

    // 1) fused pre-pass: neighbor lists + all fp32->bf16 conversions
    {
        ConvArgs a;
        const unsigned sz4[5] = {
            (unsigned)((size_t)R_SRC * E_DIM / 4),
            (unsigned)((size_t)E_DIM * E_DIM / 4),
            (unsigned)((size_t)3 * E_DIM * E_DIM / 4),
            (unsigned)((size_t)E_DIM * E_DIM / 4),
            (unsigned)((size_t)N_NODES * E_DIM / 4)};
        a.s[0] = source;  a.d[0] = src_bf;
        a.s[1] = W_trans; a.d[1] = wt_bf;
        a.s[2] = in_w;    a.d[2] = inw_bf;
        a.s[3] = out_w;   a.d[3] = outw_bf;
        a.s[4] = target;  a.d[4] = tgt_bf;
        a.off[0] = 0;
        for (int i = 0; i < 5; ++i) a.off[i + 1] = a.off[i] + sz4[i];
        const int nconv = (a.off[5] + 255) / 256;
        pre_kernel<<<N_NODES + nconv, 256, 0, stream>>>(adj, neigh, deg, a);
    }

    const size_t EE = (size_t)E_DIM * E_DIM;

    // 2) fused 256^2 dispatch: src_relu (128 blocks) + Q (16 blocks) = 144
    {
        GD256 ds, dq;
        ds.A = src_bf; ds.B = wt_bf; ds.bias = b_trans; ds.C = srcrel_bf;
        ds.N = E_DIM; ds.K = E_DIM; ds.nbx = E_DIM / 256; ds.relu = 1; ds.outbf = 1;
        ds.rowmask = nullptr;
        dq.A = tgt_bf; dq.B = inw_bf; dq.bias = in_b; dq.C = Qm;
        dq.N = E_DIM; dq.K = E_DIM; dq.nbx = E_DIM / 256; dq.relu = 0; dq.outbf = 0;
        dq.rowmask = nullptr;
        const int sblocks = (R_SRC / 256) * (E_DIM / 256);    // 128
        const int qblocks = (N_NODES / 256) * (E_DIM / 256);  // 16
        gemm256<<<sblocks + qblocks, 512, 0, stream>>>(ds, dq, sblocks);
    }

    // 3) KV = src_relu @ [Wk;Wv]^T + [bk;bv]   [R, 2E] bf16  (exactly 256 blocks)
    {
        GD256 dkv;
        dkv.A = srcrel_bf; dkv.B = inw_bf + EE; dkv.bias = in_b + E_DIM;
        dkv.C = KV_bf; dkv.N = 2 * E_DIM; dkv.K = E_DIM;
        dkv.nbx = 2 * E_DIM / 256; dkv.relu = 0; dkv.outbf = 1; dkv.rowmask = nullptr;
        const int kvblocks = (R_SRC / 256) * (2 * E_DIM / 256);  // 256
        gemm256<<<kvblocks, 512, 0, stream>>>(dkv, dkv, kvblocks);
    }

    // 4) attention -> bf16
    attn_kernel<<<N_NODES, 256, 0, stream>>>(Qm, KV_bf, neigh, deg, attn_bf);

    // 5) out = attn_out @ out_w^T + out_b, deg==0 rows zeroed  [N, E] f32
    gemm_k<64, 64, 2, 2><<<dim3(E_DIM / 64, N_NODES / 64), 256, 0, stream>>>(
        attn_bf, outw_bf, out_b, out, E_DIM, E_DIM, 0, 0, deg);
}